// Round 5
// baseline (267.554 us; speedup 1.0000x reference)
//
#include <hip/hip_runtime.h>

// GradientLoss: g(x) = sqrt(gv^2 + gh^2 + eps), loss = mean(|g(in) - g(tgt)|)
// gv[h][w] = x[h+1][w] - x[h-1][w]  (zero pad), gh[h][w] = x[h][w+1] - x[h][w-1]
// Shapes: (32, 3, 512, 512) fp32 -> 96 independent 512x512 planes. Output: 1 fp32.
//
// R8 + depth-4 register pipeline: wave = 8-row strip, lane i owns cols
// [4i..4i+3] and [256+4i..256+4i+3] (dense 16B/lane float4 loads covering the
// full 512-wide row). 10 row-slots (rows h0-1..h0+8), loads issued 3-4
// iterations ahead of use so each wave sustains ~12-16 outstanding dwordx4
// loads. Fully unrolled, static slot indices (no scratch). Horizontal
// neighbors via shfl; vertical from the register window.

constexpr int H = 512, W = 512;
constexpr int PLANES = 96;             // N*C = 32*3
constexpr int R = 8;                   // rows per strip
constexpr int SPP = H / R;             // 64 strips per plane
constexpr int NSTRIPS = PLANES * SPP;  // 6144 waves
constexpr int WPB = 4;                 // waves per block
constexpr int NBLOCKS = NSTRIPS / WPB; // 1536 blocks
constexpr float EPS = 1e-6f;
constexpr float INV_N = 1.0f / ((float)PLANES * (float)H * (float)W);

struct Row { float4 a, b; };           // cols [4i..4i+3], [256+4i..256+4i+3]

__device__ __forceinline__ Row loadRow(const float* __restrict__ p) {
    Row r;
    r.a = *reinterpret_cast<const float4*>(p);
    r.b = *reinterpret_cast<const float4*>(p + 256);
    return r;
}

__device__ __forceinline__ Row zeroRow() {
    Row r;
    r.a = make_float4(0.f, 0.f, 0.f, 0.f);
    r.b = make_float4(0.f, 0.f, 0.f, 0.f);
    return r;
}

// gradient magnitude for this lane's 8 pixels of the current row
__device__ __forceinline__ void gradRow(const Row& up, const Row& cu, const Row& dn,
                                        bool lane0, bool lane63, float g[8]) {
    float lwA = __shfl_up(cu.a.w, 1, 64);      // col 4i-1
    float rwA = __shfl_down(cu.a.x, 1, 64);    // col 4i+4
    float lwB = __shfl_up(cu.b.w, 1, 64);      // col 256+4i-1
    float rwB = __shfl_down(cu.b.x, 1, 64);    // col 256+4i+4
    const float c256 = __shfl(cu.b.x, 0, 64);  // col 256 (seam)
    const float c255 = __shfl(cu.a.w, 63, 64); // col 255 (seam)
    if (lane0)  { lwA = 0.f;  lwB = c255; }    // w=0 zero pad / seam
    if (lane63) { rwA = c256; rwB = 0.f;  }    // seam / w=511 zero pad

    const float ghA0 = cu.a.y - lwA;
    const float ghA1 = cu.a.z - cu.a.x;
    const float ghA2 = cu.a.w - cu.a.y;
    const float ghA3 = rwA    - cu.a.z;
    const float ghB0 = cu.b.y - lwB;
    const float ghB1 = cu.b.z - cu.b.x;
    const float ghB2 = cu.b.w - cu.b.y;
    const float ghB3 = rwB    - cu.b.z;

    const float gvA0 = dn.a.x - up.a.x, gvA1 = dn.a.y - up.a.y;
    const float gvA2 = dn.a.z - up.a.z, gvA3 = dn.a.w - up.a.w;
    const float gvB0 = dn.b.x - up.b.x, gvB1 = dn.b.y - up.b.y;
    const float gvB2 = dn.b.z - up.b.z, gvB3 = dn.b.w - up.b.w;

    g[0] = __builtin_amdgcn_sqrtf(fmaf(gvA0, gvA0, fmaf(ghA0, ghA0, EPS)));
    g[1] = __builtin_amdgcn_sqrtf(fmaf(gvA1, gvA1, fmaf(ghA1, ghA1, EPS)));
    g[2] = __builtin_amdgcn_sqrtf(fmaf(gvA2, gvA2, fmaf(ghA2, ghA2, EPS)));
    g[3] = __builtin_amdgcn_sqrtf(fmaf(gvA3, gvA3, fmaf(ghA3, ghA3, EPS)));
    g[4] = __builtin_amdgcn_sqrtf(fmaf(gvB0, gvB0, fmaf(ghB0, ghB0, EPS)));
    g[5] = __builtin_amdgcn_sqrtf(fmaf(gvB1, gvB1, fmaf(ghB1, ghB1, EPS)));
    g[6] = __builtin_amdgcn_sqrtf(fmaf(gvB2, gvB2, fmaf(ghB2, ghB2, EPS)));
    g[7] = __builtin_amdgcn_sqrtf(fmaf(gvB3, gvB3, fmaf(ghB3, ghB3, EPS)));
}

__global__ __launch_bounds__(256, 4) void grad_loss_kernel(
    const float* __restrict__ src0,
    const float* __restrict__ src1,
    float* __restrict__ out)
{
    const int wid   = blockIdx.x * WPB + (threadIdx.x >> 6);
    const int lane  = threadIdx.x & 63;
    const int plane = wid >> 6;            // / SPP (SPP = 64)
    const int strip = wid & 63;
    const int h0    = strip * R;

    const int base = plane * (H * W) + h0 * W + lane * 4;
    const float* __restrict__ pi = src0 + base;
    const float* __restrict__ pt = src1 + base;

    const bool lane0  = (lane == 0);
    const bool lane63 = (lane == 63);
    const bool firstStrip = (h0 == 0);     // wave-uniform
    const bool lastStrip  = (h0 + R == H); // wave-uniform

    // slot m holds global row h0+m-1 (m = 0 .. R+1); address offset (m-1)*W.
    Row wi[R + 2], wt[R + 2];

    // ---- prologue: issue loads for slots 0..3 (rows h0-1 .. h0+2) ----
    #pragma unroll
    for (int m = 0; m < 4; ++m) {
        if (m == 0 && firstStrip) {
            wi[0] = zeroRow(); wt[0] = zeroRow();
        } else {
            wi[m] = loadRow(pi + (m - 1) * W);
            wt[m] = loadRow(pt + (m - 1) * W);
        }
    }

    float acc = 0.f;

    #pragma unroll
    for (int j = 0; j < R; ++j) {
        // issue loads 3-4 iterations ahead: slot j+4 (row h0+j+3)
        constexpr int LAST = R + 1;
        const int m = j + 4;
        if (m <= LAST) {                   // compile-time per unrolled iter
            if (m == LAST && lastStrip) {
                wi[m] = zeroRow(); wt[m] = zeroRow();
            } else {
                wi[m] = loadRow(pi + (m - 1) * W);
                wt[m] = loadRow(pt + (m - 1) * W);
            }
        }

        float gi[8], gt[8];
        gradRow(wi[j], wi[j + 1], wi[j + 2], lane0, lane63, gi);
        gradRow(wt[j], wt[j + 1], wt[j + 2], lane0, lane63, gt);

        #pragma unroll
        for (int i = 0; i < 8; ++i) acc += fabsf(gi[i] - gt[i]);
    }

    // ---- wave reduction (64 lanes) ----
    #pragma unroll
    for (int off = 32; off > 0; off >>= 1)
        acc += __shfl_down(acc, off, 64);

    __shared__ float wsum[WPB];
    const int w = threadIdx.x >> 6;
    if (lane == 0) wsum[w] = acc;
    __syncthreads();

    if (threadIdx.x == 0) {
        const float s = wsum[0] + wsum[1] + wsum[2] + wsum[3];
        atomicAdd(out, s * INV_N);
    }
}

extern "C" void kernel_launch(void* const* d_in, const int* in_sizes, int n_in,
                              void* d_out, int out_size, void* d_ws, size_t ws_size,
                              hipStream_t stream) {
    const float* in  = (const float*)d_in[0];
    const float* tgt = (const float*)d_in[1];
    float* out = (float*)d_out;

    // d_out is poisoned with 0xAA before every launch — zero it first.
    hipMemsetAsync(out, 0, sizeof(float), stream);

    grad_loss_kernel<<<NBLOCKS, 64 * WPB, 0, stream>>>(in, tgt, out);
}

// Round 6
// 234.665 us; speedup vs baseline: 1.1402x; 1.1402x over previous
//
#include <hip/hip_runtime.h>

// GradientLoss: g(x) = sqrt(gv^2 + gh^2 + eps), loss = mean(|g(in) - g(tgt)|)
// gv[h][w] = x[h+1][w] - x[h-1][w]  (zero pad), gh[h][w] = x[h][w+1] - x[h][w-1]
// Shapes: (32, 3, 512, 512) fp32 -> 96 planes of 512x512. Output: 1 fp32.
//
// LDS-staged stencil: block (4 waves) = 8-row strip of one plane. Prologue
// issues 10 KB/wave of global_load_lds (width 16) covering rows h0-1..h0+8
// for both tensors (40 KB LDS), one __syncthreads (drains vmcnt), then all
// compute reads LDS. Deep MLP without register pressure: ~40 KB in flight
// per block, no register row-window, no spills. Boundary rows are zero-filled
// in LDS so vertical padding needs no masks.

constexpr int H = 512, W = 512;
constexpr int PLANES = 96;             // N*C = 32*3
constexpr int R = 8;                   // rows computed per block
constexpr int LR = R + 2;              // rows staged (with halo) = 10
constexpr int SPP = H / R;             // 64 strips per plane
constexpr int NBLOCKS = PLANES * SPP;  // 6144 blocks
constexpr float EPS = 1e-6f;
constexpr float INV_N = 1.0f / ((float)PLANES * (float)H * (float)W);

// per-tensor staged region: LR*W floats = 20480 B; per wave: LR*W/4 floats
constexpr int REGION_F = LR * W;           // 5120 floats
constexpr int WCHUNK_F = REGION_F / 4;     // 1280 floats (5 KB) per wave
constexpr int ICHUNK_F = 256;              // 1 KB per global_load_lds instr

typedef __attribute__((address_space(3))) void lds_void_t;
typedef __attribute__((address_space(1))) const void gbl_void_t;

__device__ __forceinline__ void gll16(const float* g, float* l) {
    __builtin_amdgcn_global_load_lds((gbl_void_t*)g, (lds_void_t*)l, 16, 0, 0);
}

__global__ __launch_bounds__(256) void grad_loss_kernel(
    const float* __restrict__ src0,
    const float* __restrict__ src1,
    float* __restrict__ out)
{
    __shared__ float lds[2][LR][W];        // 40960 B

    const int tid   = threadIdx.x;
    const int lane  = tid & 63;
    const int wv    = tid >> 6;            // wave id 0..3
    const int plane = blockIdx.x >> 6;     // / SPP (SPP = 64)
    const int strip = blockIdx.x & 63;
    const int h0    = strip * R;

    const bool firstStrip = (h0 == 0);
    const bool lastStrip  = (h0 + R == H);

    // ---- stage rows h0-1 .. h0+R into LDS (both tensors) ----
    const float* gsrc[2] = { src0, src1 };
    #pragma unroll
    for (int t = 0; t < 2; ++t) {
        // global start of the staged region (row h0-1); may be 1 row before
        // the plane for strip 0 — those chunks are skipped (zero-filled).
        const float* gbase = gsrc[t] + (size_t)plane * (H * W) + (h0 - 1) * W
                           + wv * WCHUNK_F;
        float* lbase = &lds[t][0][0] + wv * WCHUNK_F;

        #pragma unroll
        for (int i = 0; i < WCHUNK_F / ICHUNK_F; ++i) {   // 5 chunks of 1 KB
            const int byte_off = wv * (WCHUNK_F * 4) + i * (ICHUNK_F * 4);
            const bool invalid =
                (firstStrip && byte_off < (int)(W * sizeof(float))) ||
                (lastStrip  && byte_off >= (int)((LR - 1) * W * sizeof(float)));
            if (invalid) {                 // wave-uniform: zero-fill this 1 KB
                *reinterpret_cast<float4*>(lbase + i * ICHUNK_F + lane * 4) =
                    make_float4(0.f, 0.f, 0.f, 0.f);
            } else {                       // 1 KB async global->LDS per wave
                gll16(gbase + i * ICHUNK_F + lane * 4, lbase + i * ICHUNK_F);
            }
        }
    }

    __syncthreads();   // drains vmcnt(0)+lgkmcnt(0): all staging complete

    // ---- compute 8 rows x 512 cols x 2 tensors from LDS ----
    // thread -> cols [c0..c0+3], rows k = (tid>>7) + 2*rr  (rr = 0..3)
    const int c0   = (tid & 127) << 2;
    const int half = tid >> 7;
    const float lm = (c0 > 0)       ? 1.f : 0.f;   // left-edge mask (col c0-1)
    const float rm = (c0 + 4 < W)   ? 1.f : 0.f;   // right-edge mask (col c0+4)
    const int  lc  = (c0 > 0)       ? c0 - 2 : 0;  // aligned b64 holding col c0-1
    const int  rc  = (c0 + 4 < W)   ? c0 + 4 : W - 4; // aligned b64 holding col c0+4

    float acc = 0.f;

    #pragma unroll
    for (int rr = 0; rr < 4; ++rr) {
        const int k = half + (rr << 1);    // output row within strip, 0..7
        float g[2][4];

        #pragma unroll
        for (int t = 0; t < 2; ++t) {
            const float4 up = *reinterpret_cast<const float4*>(&lds[t][k    ][c0]);
            const float4 cu = *reinterpret_cast<const float4*>(&lds[t][k + 1][c0]);
            const float4 dn = *reinterpret_cast<const float4*>(&lds[t][k + 2][c0]);
            const float2 l2 = *reinterpret_cast<const float2*>(&lds[t][k + 1][lc]);
            const float2 r2 = *reinterpret_cast<const float2*>(&lds[t][k + 1][rc]);

            const float gh0 = cu.y - l2.y * lm;
            const float gh1 = cu.z - cu.x;
            const float gh2 = cu.w - cu.y;
            const float gh3 = r2.x * rm - cu.z;

            const float gv0 = dn.x - up.x;
            const float gv1 = dn.y - up.y;
            const float gv2 = dn.z - up.z;
            const float gv3 = dn.w - up.w;

            g[t][0] = __builtin_amdgcn_sqrtf(fmaf(gv0, gv0, fmaf(gh0, gh0, EPS)));
            g[t][1] = __builtin_amdgcn_sqrtf(fmaf(gv1, gv1, fmaf(gh1, gh1, EPS)));
            g[t][2] = __builtin_amdgcn_sqrtf(fmaf(gv2, gv2, fmaf(gh2, gh2, EPS)));
            g[t][3] = __builtin_amdgcn_sqrtf(fmaf(gv3, gv3, fmaf(gh3, gh3, EPS)));
        }

        acc += fabsf(g[0][0] - g[1][0]) + fabsf(g[0][1] - g[1][1])
             + fabsf(g[0][2] - g[1][2]) + fabsf(g[0][3] - g[1][3]);
    }

    // ---- wave reduction (64 lanes) ----
    #pragma unroll
    for (int off = 32; off > 0; off >>= 1)
        acc += __shfl_down(acc, off, 64);

    __shared__ float wsum[4];
    if (lane == 0) wsum[wv] = acc;
    __syncthreads();

    if (tid == 0) {
        const float s = wsum[0] + wsum[1] + wsum[2] + wsum[3];
        atomicAdd(out, s * INV_N);
    }
}

extern "C" void kernel_launch(void* const* d_in, const int* in_sizes, int n_in,
                              void* d_out, int out_size, void* d_ws, size_t ws_size,
                              hipStream_t stream) {
    const float* in  = (const float*)d_in[0];
    const float* tgt = (const float*)d_in[1];
    float* out = (float*)d_out;

    // d_out is poisoned with 0xAA before every launch — zero it first.
    hipMemsetAsync(out, 0, sizeof(float), stream);

    grad_loss_kernel<<<NBLOCKS, 256, 0, stream>>>(in, tgt, out);
}

// Round 7
// 214.026 us; speedup vs baseline: 1.2501x; 1.0964x over previous
//
#include <hip/hip_runtime.h>

// GradientLoss: g(x) = sqrt(gv^2 + gh^2 + eps), loss = mean(|g(in) - g(tgt)|)
// gv[h][w] = x[h+1][w] - x[h-1][w]  (zero pad), gh[h][w] = x[h][w+1] - x[h][w-1]
// Shapes: (32, 3, 512, 512) fp32 -> 96 planes of 512x512. Output: 1 fp32.
//
// R8 + depth-4 register pipeline (retry of round-5 WITHOUT the VGPR cap that
// caused 180 MB of scratch spills). Wave = 8-row strip; lane i owns cols
// [4i..4i+3] and [256+4i..256+4i+3] (dense 16B/lane float4, full 512-wide
// row). 10 row-slots; loads for slot j+4 issue in iteration j and are first
// consumed in iteration j+2 -> ~8-16 outstanding dwordx4 per wave. ~5 slots
// live at once (~80 data VGPRs); NO __launch_bounds__ min-wave clamp so the
// allocator can take ~150 VGPRs without spilling.

constexpr int H = 512, W = 512;
constexpr int PLANES = 96;             // N*C = 32*3
constexpr int R = 8;                   // rows per strip
constexpr int SPP = H / R;             // 64 strips per plane
constexpr int NSTRIPS = PLANES * SPP;  // 6144 waves
constexpr int WPB = 4;                 // waves per block
constexpr int NBLOCKS = NSTRIPS / WPB; // 1536 blocks
constexpr float EPS = 1e-6f;
constexpr float INV_N = 1.0f / ((float)PLANES * (float)H * (float)W);

struct Row { float4 a, b; };           // cols [4i..4i+3], [256+4i..256+4i+3]

__device__ __forceinline__ Row loadRow(const float* __restrict__ p) {
    Row r;
    r.a = *reinterpret_cast<const float4*>(p);
    r.b = *reinterpret_cast<const float4*>(p + 256);
    return r;
}

__device__ __forceinline__ Row zeroRow() {
    Row r;
    r.a = make_float4(0.f, 0.f, 0.f, 0.f);
    r.b = make_float4(0.f, 0.f, 0.f, 0.f);
    return r;
}

// gradient magnitude for this lane's 8 pixels of the current row
__device__ __forceinline__ void gradRow(const Row& up, const Row& cu, const Row& dn,
                                        bool lane0, bool lane63, float g[8]) {
    float lwA = __shfl_up(cu.a.w, 1, 64);      // col 4i-1
    float rwA = __shfl_down(cu.a.x, 1, 64);    // col 4i+4
    float lwB = __shfl_up(cu.b.w, 1, 64);      // col 256+4i-1
    float rwB = __shfl_down(cu.b.x, 1, 64);    // col 256+4i+4
    const float c256 = __shfl(cu.b.x, 0, 64);  // col 256 (seam)
    const float c255 = __shfl(cu.a.w, 63, 64); // col 255 (seam)
    if (lane0)  { lwA = 0.f;  lwB = c255; }    // w=0 zero pad / seam
    if (lane63) { rwA = c256; rwB = 0.f;  }    // seam / w=511 zero pad

    const float ghA0 = cu.a.y - lwA;
    const float ghA1 = cu.a.z - cu.a.x;
    const float ghA2 = cu.a.w - cu.a.y;
    const float ghA3 = rwA    - cu.a.z;
    const float ghB0 = cu.b.y - lwB;
    const float ghB1 = cu.b.z - cu.b.x;
    const float ghB2 = cu.b.w - cu.b.y;
    const float ghB3 = rwB    - cu.b.z;

    const float gvA0 = dn.a.x - up.a.x, gvA1 = dn.a.y - up.a.y;
    const float gvA2 = dn.a.z - up.a.z, gvA3 = dn.a.w - up.a.w;
    const float gvB0 = dn.b.x - up.b.x, gvB1 = dn.b.y - up.b.y;
    const float gvB2 = dn.b.z - up.b.z, gvB3 = dn.b.w - up.b.w;

    g[0] = __builtin_amdgcn_sqrtf(fmaf(gvA0, gvA0, fmaf(ghA0, ghA0, EPS)));
    g[1] = __builtin_amdgcn_sqrtf(fmaf(gvA1, gvA1, fmaf(ghA1, ghA1, EPS)));
    g[2] = __builtin_amdgcn_sqrtf(fmaf(gvA2, gvA2, fmaf(ghA2, ghA2, EPS)));
    g[3] = __builtin_amdgcn_sqrtf(fmaf(gvA3, gvA3, fmaf(ghA3, ghA3, EPS)));
    g[4] = __builtin_amdgcn_sqrtf(fmaf(gvB0, gvB0, fmaf(ghB0, ghB0, EPS)));
    g[5] = __builtin_amdgcn_sqrtf(fmaf(gvB1, gvB1, fmaf(ghB1, ghB1, EPS)));
    g[6] = __builtin_amdgcn_sqrtf(fmaf(gvB2, gvB2, fmaf(ghB2, ghB2, EPS)));
    g[7] = __builtin_amdgcn_sqrtf(fmaf(gvB3, gvB3, fmaf(ghB3, ghB3, EPS)));
}

__global__ __launch_bounds__(256) void grad_loss_kernel(
    const float* __restrict__ src0,
    const float* __restrict__ src1,
    float* __restrict__ out)
{
    const int wid   = blockIdx.x * WPB + (threadIdx.x >> 6);
    const int lane  = threadIdx.x & 63;
    const int plane = wid >> 6;            // / SPP (SPP = 64)
    const int strip = wid & 63;
    const int h0    = strip * R;

    const int base = plane * (H * W) + h0 * W + lane * 4;
    const float* __restrict__ pi = src0 + base;
    const float* __restrict__ pt = src1 + base;

    const bool lane0  = (lane == 0);
    const bool lane63 = (lane == 63);
    const bool firstStrip = (h0 == 0);     // wave-uniform
    const bool lastStrip  = (h0 + R == H); // wave-uniform

    // slot m holds global row h0+m-1 (m = 0 .. R+1); address offset (m-1)*W.
    Row wi[R + 2], wt[R + 2];

    // ---- prologue: issue loads for slots 0..3 (rows h0-1 .. h0+2) ----
    #pragma unroll
    for (int m = 0; m < 4; ++m) {
        if (m == 0 && firstStrip) {
            wi[0] = zeroRow(); wt[0] = zeroRow();
        } else {
            wi[m] = loadRow(pi + (m - 1) * W);
            wt[m] = loadRow(pt + (m - 1) * W);
        }
    }

    float acc = 0.f;

    #pragma unroll
    for (int j = 0; j < R; ++j) {
        // issue loads 3-4 iterations ahead of first use: slot j+4
        constexpr int LAST = R + 1;
        const int m = j + 4;
        if (m <= LAST) {                   // compile-time per unrolled iter
            if (m == LAST && lastStrip) {
                wi[m] = zeroRow(); wt[m] = zeroRow();
            } else {
                wi[m] = loadRow(pi + (m - 1) * W);
                wt[m] = loadRow(pt + (m - 1) * W);
            }
        }

        float gi[8], gt[8];
        gradRow(wi[j], wi[j + 1], wi[j + 2], lane0, lane63, gi);
        gradRow(wt[j], wt[j + 1], wt[j + 2], lane0, lane63, gt);

        #pragma unroll
        for (int i = 0; i < 8; ++i) acc += fabsf(gi[i] - gt[i]);
    }

    // ---- wave reduction (64 lanes) ----
    #pragma unroll
    for (int off = 32; off > 0; off >>= 1)
        acc += __shfl_down(acc, off, 64);

    __shared__ float wsum[WPB];
    const int w = threadIdx.x >> 6;
    if (lane == 0) wsum[w] = acc;
    __syncthreads();

    if (threadIdx.x == 0) {
        const float s = wsum[0] + wsum[1] + wsum[2] + wsum[3];
        atomicAdd(out, s * INV_N);
    }
}

extern "C" void kernel_launch(void* const* d_in, const int* in_sizes, int n_in,
                              void* d_out, int out_size, void* d_ws, size_t ws_size,
                              hipStream_t stream) {
    const float* in  = (const float*)d_in[0];
    const float* tgt = (const float*)d_in[1];
    float* out = (float*)d_out;

    // d_out is poisoned with 0xAA before every launch — zero it first.
    hipMemsetAsync(out, 0, sizeof(float), stream);

    grad_loss_kernel<<<NBLOCKS, 64 * WPB, 0, stream>>>(in, tgt, out);
}